// Round 11
// baseline (266.310 us; speedup 1.0000x reference)
//
#include <hip/hip_runtime.h>

typedef unsigned short u16;
typedef unsigned int   u32;
typedef unsigned long long u64;
typedef signed char    i8;

typedef int   i32x4  __attribute__((ext_vector_type(4)));
typedef int   i32x16 __attribute__((ext_vector_type(16)));

#define IN_F   4096
#define OUT_F  11008
#define TOKENS 4096

#define BM 256
#define BN 256
#define BKQ 128              // K per tile in i8 elems = 128B rows
#define MT (TOKENS / BM)     // 16
#define NT (OUT_F / BN)      // 43
#define KTILES (IN_F / BKQ)  // 32

// direct global->LDS async copy, 16B per lane; LDS dest = wave-uniform base + lane*16
#define GLOAD_LDS16(g, l)                                                        \
    __builtin_amdgcn_global_load_lds(                                            \
        (const __attribute__((address_space(1))) u32*)(u64)(g),                  \
        (__attribute__((address_space(3))) u32*)(u64)(l), 16, 0, 0)

#define BAR() __builtin_amdgcn_s_barrier()
#define VM(N)    asm volatile("s_waitcnt vmcnt(" #N ")" ::: "memory")
#define LGKM(N)  asm volatile("s_waitcnt lgkmcnt(" #N ")" ::: "memory")

__device__ __forceinline__ int pack4(int a, int b, int c, int d) {
    return (a & 255) | ((b & 255) << 8) | ((c & 255) << 16) | (d << 24);
}

// ------- prep_x: f32 -> i8 per-row symmetric quant + exact f32 rowsum --------
__global__ __launch_bounds__(256) void prep_x_kernel(
    const float* __restrict__ x, i8* __restrict__ xq,
    float* __restrict__ rowsum, float* __restrict__ rowscale) {
    const int row = blockIdx.x;
    const int tid = threadIdx.x;
    const float4* xr = reinterpret_cast<const float4*>(x + (size_t)row * IN_F);
    float4 v[4];
    float s = 0.f, mx = 0.f;
#pragma unroll
    for (int i = 0; i < 4; ++i) {
        v[i] = xr[tid * 4 + i];
        s += v[i].x + v[i].y + v[i].z + v[i].w;
        mx = fmaxf(mx, fmaxf(fmaxf(fabsf(v[i].x), fabsf(v[i].y)),
                             fmaxf(fabsf(v[i].z), fabsf(v[i].w))));
    }
#pragma unroll
    for (int off = 32; off > 0; off >>= 1) {
        s += __shfl_down(s, off, 64);
        mx = fmaxf(mx, __shfl_down(mx, off, 64));
    }
    __shared__ float ss[4], sm[4];
    if ((tid & 63) == 0) { ss[tid >> 6] = s; sm[tid >> 6] = mx; }
    __syncthreads();
    const float tot = ss[0] + ss[1] + ss[2] + ss[3];
    const float m4  = fmaxf(fmaxf(sm[0], sm[1]), fmaxf(sm[2], sm[3]));
    const float mg  = fmaxf(m4, 1e-20f);
    const float inv = 127.0f / mg;
    if (tid == 0) { rowsum[row] = tot; rowscale[row] = mg * (1.0f / 127.0f); }
    int4 o;
    int q[16];
#pragma unroll
    for (int i = 0; i < 4; ++i) {
        q[4 * i + 0] = (int)rintf(v[i].x * inv);
        q[4 * i + 1] = (int)rintf(v[i].y * inv);
        q[4 * i + 2] = (int)rintf(v[i].z * inv);
        q[4 * i + 3] = (int)rintf(v[i].w * inv);
    }
    o.x = pack4(q[0], q[1], q[2], q[3]);
    o.y = pack4(q[4], q[5], q[6], q[7]);
    o.z = pack4(q[8], q[9], q[10], q[11]);
    o.w = pack4(q[12], q[13], q[14], q[15]);
    reinterpret_cast<int4*>(xq + (size_t)row * IN_F)[tid] = o;
}

// ---------------- prep_w: int32 (0..255) -> i8 (wq - 128, exact) ----------------
__global__ __launch_bounds__(256) void prep_w_kernel(
    const int* __restrict__ wq, i8* __restrict__ wb) {
    const size_t total16 = (size_t)OUT_F * IN_F / 16;
    size_t i = (size_t)blockIdx.x * blockDim.x + threadIdx.x;
    const size_t stride = (size_t)gridDim.x * blockDim.x;
    const int4* p = reinterpret_cast<const int4*>(wq);
    int4* o = reinterpret_cast<int4*>(wb);
    for (; i < total16; i += stride) {
        int4 a = p[i * 4], b = p[i * 4 + 1], c = p[i * 4 + 2], d = p[i * 4 + 3];
        int4 v;
        v.x = pack4(a.x - 128, a.y - 128, a.z - 128, a.w - 128);
        v.y = pack4(b.x - 128, b.y - 128, b.z - 128, b.w - 128);
        v.z = pack4(c.x - 128, c.y - 128, c.z - 128, c.w - 128);
        v.w = pack4(d.x - 128, d.y - 128, d.z - 128, d.w - 128);
        o[i] = v;
    }
}

// ------- qgemm: 8-phase i8 schedule, mfma_i32_32x32x32_i8 ----------
// y[t,o] = scale_o*sx_t*S_to + scale_o*(128-zero_o)*rowsum_t + bias_o
//
// r10 geometry/schedule, MFMA shape 16x16x64 -> 32x32x32 (µbench 3944 -> 4404
// TOPS, half the instructions per phase; per-phase ds_reads/regs unchanged).
// Wave output 128x64 = 4m x 2n frags of 32x32; K-tile = 4 k-steps of 32.
// A-frag: lane l holds A[row = base + (l&31)][k = s*32 + (l>>5)*16 .. +16)
// B-frag: lane l holds B[col = base + (l&31)][same k]  (byte-analog of the
// verified 32x32x16 bf16 mapping, same analogy that held for 16x16 in r7).
// C/D: col = lane&31, row = (reg&3) + 8*(reg>>2) + 4*(lane>>5)  [m74/m101;
// dtype-independent per m121-128].
// Swizzle: LDS slot = global 16B-slot ^ (row&7) (stage pre-swizzles source,
// rule 21); read global slot g = s*2 + (lane>>5) -> LDS slot g ^ (lane&7).
// Every 8 consecutive lanes cover all 8 slots -> conflict-free (r4 criterion).

#define LDA_HALF(P, MH)                                                           \
    _Pragma("unroll") for (int mi = 0; mi < 2; ++mi)                              \
    _Pragma("unroll") for (int s = 0; s < 2; ++s) {                               \
        af[mi][2 * s]     = *(const i32x4*)((const char*)&AS[P][0] +              \
            ((wr * 128 + (MH) * 64 + mi * 32 + l31) * 128 +                       \
             (((2 * s + 0) * 2 + lh) ^ l7) * 16));                                \
        af[mi][2 * s + 1] = *(const i32x4*)((const char*)&AS[P][0] +              \
            ((wr * 128 + (MH) * 64 + mi * 32 + l31) * 128 +                       \
             (((2 * s + 1) * 2 + lh) ^ l7) * 16));                                \
    }

#define LDB_HALF(P, NH)                                                           \
    _Pragma("unroll") for (int s = 0; s < 4; ++s)                                 \
        bfr[NH][s] = *(const i32x4*)((const char*)&BS[P][0] +                     \
            ((wc * 64 + (NH) * 32 + l31) * 128 + ((s * 2 + lh) ^ l7) * 16));

#define MFMA_Q(MH, NH)                                                            \
    __builtin_amdgcn_s_setprio(1);                                                \
    _Pragma("unroll") for (int mi = 0; mi < 2; ++mi)                              \
    _Pragma("unroll") for (int s = 0; s < 4; ++s)                                 \
        acc[(MH) * 2 + mi][NH] = __builtin_amdgcn_mfma_i32_32x32x32_i8(           \
            af[mi][s], bfr[NH][s], acc[(MH) * 2 + mi][NH], 0, 0, 0);              \
    __builtin_amdgcn_s_setprio(0);

// A half-region H of k-tile KT into buf P: 16 chunks of 1KB, 2/wave.
#define STAGE_A(P, H, KT) {                                                       \
    _Pragma("unroll") for (int j = 0; j < 2; ++j) {                               \
        const int i_ = 2 * w + j;                                                 \
        const int chunk = (((H) * 8 + (i_ & 7) + ((i_ >> 3) << 4)) << 10);        \
        const int row_ = (chunk + lane * 16) >> 7;                                \
        const int cb_ = (((lane & 7) ^ (row_ & 7)) << 4);                         \
        const i8* g_ = Abase + (size_t)row_ * IN_F + (KT) * BKQ + cb_;            \
        GLOAD_LDS16(g_, (char*)&AS[P][0] + chunk);                                \
    } }

// B half-region H: chunk = H*4 + (i&3) + (i>>2)*8
#define STAGE_B(P, H, KT) {                                                       \
    _Pragma("unroll") for (int j = 0; j < 2; ++j) {                               \
        const int i_ = 2 * w + j;                                                 \
        const int chunk = (((H) * 4 + (i_ & 3) + ((i_ >> 2) << 3)) << 10);        \
        const int row_ = (chunk + lane * 16) >> 7;                                \
        const int cb_ = (((lane & 7) ^ (row_ & 7)) << 4);                         \
        const i8* g_ = Bbase + (size_t)row_ * IN_F + (KT) * BKQ + cb_;            \
        GLOAD_LDS16(g_, (char*)&BS[P][0] + chunk);                                \
    } }

__global__ __launch_bounds__(512, 1) void qgemm_kernel(
    const i8* __restrict__ Xq, const i8* __restrict__ Wqb,
    const float* __restrict__ rowsum, const float* __restrict__ rowscale,
    const float* __restrict__ scale, const float* __restrict__ zero,
    const float* __restrict__ bias, float* __restrict__ out) {
    __shared__ i8 AS[2][BM * BKQ];  // 2 x 32KB
    __shared__ i8 BS[2][BN * BKQ];  // 2 x 32KB

    // XCD map: xcd owns 2mt x 43nt
    const int bid = blockIdx.x;
    const int xcd = bid & 7;
    const int g   = bid >> 3;            // 0..85
    const int mt  = xcd * 2 + (g & 1);
    const int nt  = g >> 1;

    const int tid  = threadIdx.x;
    const int w    = tid >> 6;        // wave 0..7
    const int lane = tid & 63;
    const int wr   = w >> 2;          // wave row half 0..1 (128 rows each)
    const int wc   = w & 3;           // wave col 0..3 (64 cols each)
    const int l31  = lane & 31;
    const int l7   = lane & 7;
    const int lh   = lane >> 5;       // K-sub-half selector for 32x32 frags

    const i8* Abase = Xq  + (size_t)mt * BM * IN_F;
    const i8* Bbase = Wqb + (size_t)nt * BN * IN_F;

    i32x4 af[2][4];
    i32x4 bfr[2][4];
    i32x16 acc[4][2];
#pragma unroll
    for (int m = 0; m < 4; ++m)
#pragma unroll
        for (int n = 0; n < 2; ++n) acc[m][n] = (i32x16)(0);

    // ---- prologue: 7 half-stages in steady-state FIFO order ----
    STAGE_A(0, 0, 0);   // Ah0(0)
    STAGE_B(0, 0, 0);   // Bh0(0)
    STAGE_B(0, 1, 0);   // Bh1(0)
    STAGE_A(0, 1, 0);   // Ah1(0)
    STAGE_A(1, 0, 1);   // Ah0(1)
    STAGE_B(1, 0, 1);   // Bh0(1)
    STAGE_B(1, 1, 1);   // Bh1(1)
    VM(6);              // retires ALL of tile 0 (covers P1-P3 reads)
    BAR();

    // ---- steady loop: 15 iterations, tiles 0..29 (stages through 31) ----
    for (int i = 0; i < 15; ++i) {
        const int t = 2 * i;
        // P1
        LDA_HALF(0, 0); LDB_HALF(0, 0);
        STAGE_A(1, 1, t + 1);
        LGKM(8);
        BAR();
        LGKM(0);
        MFMA_Q(0, 0);
        BAR();
        // P2
        LDB_HALF(0, 1);
        STAGE_A(0, 0, t + 2);
        BAR();
        LGKM(0);
        MFMA_Q(0, 1);
        BAR();
        // P3
        LDA_HALF(0, 1);
        STAGE_B(0, 0, t + 2);
        BAR();
        LGKM(0);
        MFMA_Q(1, 0);
        BAR();
        // P4
        STAGE_B(0, 1, t + 2);
        BAR();
        MFMA_Q(1, 1);
        VM(6); BAR();   // retires {Ah0,Bh0,Bh1,Ah1}(t+1) -> covers P5-P7
        // P5
        LDA_HALF(1, 0); LDB_HALF(1, 0);
        STAGE_A(0, 1, t + 2);
        LGKM(8);
        BAR();
        LGKM(0);
        MFMA_Q(0, 0);
        BAR();
        // P6
        LDB_HALF(1, 1);
        STAGE_A(1, 0, t + 3);
        BAR();
        LGKM(0);
        MFMA_Q(0, 1);
        BAR();
        // P7
        LDA_HALF(1, 1);
        STAGE_B(1, 0, t + 3);
        BAR();
        LGKM(0);
        MFMA_Q(1, 0);
        BAR();
        // P8
        STAGE_B(1, 1, t + 3);
        BAR();
        MFMA_Q(1, 1);
        VM(6); BAR();   // retires {Ah0,Bh0,Bh1,Ah1}(t+2) -> covers next P1-P3
    }

    // ---- peeled final iteration: tiles 30 (buf0), 31 (buf1) ----
    // P1
    LDA_HALF(0, 0); LDB_HALF(0, 0);
    STAGE_A(1, 1, 31);
    BAR();
    LGKM(0);
    MFMA_Q(0, 0);
    BAR();
    // P2
    LDB_HALF(0, 1);
    BAR();
    LGKM(0);
    MFMA_Q(0, 1);
    BAR();
    // P3
    LDA_HALF(0, 1);
    BAR();
    LGKM(0);
    MFMA_Q(1, 0);
    BAR();
    // P4
    BAR();
    MFMA_Q(1, 1);
    VM(0); BAR();   // drain: all tile-31 stages landed
    // P5
    LDA_HALF(1, 0); LDB_HALF(1, 0);
    BAR();
    LGKM(0);
    MFMA_Q(0, 0);
    BAR();
    // P6
    LDB_HALF(1, 1);
    BAR();
    LGKM(0);
    MFMA_Q(0, 1);
    BAR();
    // P7
    LDA_HALF(1, 1);
    BAR();
    LGKM(0);
    MFMA_Q(1, 0);
    BAR();
    // P8
    BAR();
    MFMA_Q(1, 1);

    // ---- epilogue: 32x32 C/D layout col=lane&31, row=(r&3)+8*(r>>2)+4*(lane>>5) ----
    // y = scale*sx*S + scale*(128-zero)*rowsum + bias
    const int rowt = mt * BM + wr * 128;
    const int colt = nt * BN + wc * 64;
    const int lh4  = lh * 4;

    float scn[2], bcn[2], ccn[2];
#pragma unroll
    for (int n = 0; n < 2; ++n) {
        const int col = colt + n * 32 + l31;
        scn[n] = scale[col];
        bcn[n] = scn[n] * (128.0f - zero[col]);
        ccn[n] = bias[col];
    }
#pragma unroll
    for (int mi = 0; mi < 4; ++mi) {
#pragma unroll
        for (int r = 0; r < 16; ++r) {
            const int row = rowt + mi * 32 + (r & 3) + 8 * (r >> 2) + lh4;
            const float rsv = rowsum[row];
            const float sxv = rowscale[row];
#pragma unroll
            for (int n = 0; n < 2; ++n) {
                out[(size_t)row * OUT_F + colt + n * 32 + l31] =
                    scn[n] * (sxv * (float)acc[mi][n][r]) + bcn[n] * rsv + ccn[n];
            }
        }
    }
}

extern "C" void kernel_launch(void* const* d_in, const int* in_sizes, int n_in,
                              void* d_out, int out_size, void* d_ws, size_t ws_size,
                              hipStream_t stream) {
    const float* x     = (const float*)d_in[0];
    const int*   wq    = (const int*)d_in[1];
    const float* scale = (const float*)d_in[2];
    const float* zero  = (const float*)d_in[3];
    const float* bias  = (const float*)d_in[4];
    float* out = (float*)d_out;

    // workspace: Wq' i8 (45.1 MB) | Xq i8 (16.8 MB) | rowsum (16 KB) | rowscale (16 KB)
    char* ws = (char*)d_ws;
    i8* Wqb = (i8*)ws;
    i8* Xq  = (i8*)(ws + (size_t)OUT_F * IN_F);
    float* rowsum   = (float*)(ws + (size_t)OUT_F * IN_F + (size_t)TOKENS * IN_F);
    float* rowscale = rowsum + TOKENS;

    prep_w_kernel<<<2048, 256, 0, stream>>>(wq, Wqb);
    prep_x_kernel<<<TOKENS, 256, 0, stream>>>(x, Xq, rowsum, rowscale);
    qgemm_kernel<<<MT * NT, 512, 0, stream>>>(Xq, Wqb, rowsum, rowscale,
                                              scale, zero, bias, out);
}

// Round 13
// 263.952 us; speedup vs baseline: 1.0089x; 1.0089x over previous
//
#include <hip/hip_runtime.h>

typedef unsigned short u16;
typedef unsigned int   u32;
typedef unsigned long long u64;
typedef signed char    i8;

typedef int   i32x4 __attribute__((ext_vector_type(4)));

#define IN_F   4096
#define OUT_F  11008
#define TOKENS 4096

#define BM 256
#define BN 128
#define BKQ 64               // K per tile in i8 elems = 64B rows
#define MT (TOKENS / BM)     // 16
#define NT (OUT_F / BN)      // 86
#define KTILES (IN_F / BKQ)  // 64

// direct global->LDS async copy, 16B per lane; LDS dest = wave-uniform base + lane*16
#define GLOAD_LDS16(g, l)                                                        \
    __builtin_amdgcn_global_load_lds(                                            \
        (const __attribute__((address_space(1))) u32*)(u64)(g),                  \
        (__attribute__((address_space(3))) u32*)(u64)(l), 16, 0, 0)

#define BAR() __builtin_amdgcn_s_barrier()
#define VM(N) asm volatile("s_waitcnt vmcnt(" #N ")" ::: "memory")

__device__ __forceinline__ int pack4(int a, int b, int c, int d) {
    return (a & 255) | ((b & 255) << 8) | ((c & 255) << 16) | (d << 24);
}

// ------- prep_x: f32 -> i8 per-row symmetric quant + exact f32 rowsum --------
__global__ __launch_bounds__(256) void prep_x_kernel(
    const float* __restrict__ x, i8* __restrict__ xq,
    float* __restrict__ rowsum, float* __restrict__ rowscale) {
    const int row = blockIdx.x;
    const int tid = threadIdx.x;
    const float4* xr = reinterpret_cast<const float4*>(x + (size_t)row * IN_F);
    float4 v[4];
    float s = 0.f, mx = 0.f;
#pragma unroll
    for (int i = 0; i < 4; ++i) {
        v[i] = xr[tid * 4 + i];
        s += v[i].x + v[i].y + v[i].z + v[i].w;
        mx = fmaxf(mx, fmaxf(fmaxf(fabsf(v[i].x), fabsf(v[i].y)),
                             fmaxf(fabsf(v[i].z), fabsf(v[i].w))));
    }
#pragma unroll
    for (int off = 32; off > 0; off >>= 1) {
        s += __shfl_down(s, off, 64);
        mx = fmaxf(mx, __shfl_down(mx, off, 64));
    }
    __shared__ float ss[4], sm[4];
    if ((tid & 63) == 0) { ss[tid >> 6] = s; sm[tid >> 6] = mx; }
    __syncthreads();
    const float tot = ss[0] + ss[1] + ss[2] + ss[3];
    const float m4  = fmaxf(fmaxf(sm[0], sm[1]), fmaxf(sm[2], sm[3]));
    const float mg  = fmaxf(m4, 1e-20f);
    const float inv = 127.0f / mg;
    if (tid == 0) { rowsum[row] = tot; rowscale[row] = mg * (1.0f / 127.0f); }
    int4 o;
    int q[16];
#pragma unroll
    for (int i = 0; i < 4; ++i) {
        q[4 * i + 0] = (int)rintf(v[i].x * inv);
        q[4 * i + 1] = (int)rintf(v[i].y * inv);
        q[4 * i + 2] = (int)rintf(v[i].z * inv);
        q[4 * i + 3] = (int)rintf(v[i].w * inv);
    }
    o.x = pack4(q[0], q[1], q[2], q[3]);
    o.y = pack4(q[4], q[5], q[6], q[7]);
    o.z = pack4(q[8], q[9], q[10], q[11]);
    o.w = pack4(q[12], q[13], q[14], q[15]);
    reinterpret_cast<int4*>(xq + (size_t)row * IN_F)[tid] = o;
}

// ---------------- prep_w: int32 (0..255) -> i8 (wq - 128, exact) ----------------
__global__ __launch_bounds__(256) void prep_w_kernel(
    const int* __restrict__ wq, i8* __restrict__ wb) {
    const size_t total16 = (size_t)OUT_F * IN_F / 16;
    size_t i = (size_t)blockIdx.x * blockDim.x + threadIdx.x;
    const size_t stride = (size_t)gridDim.x * blockDim.x;
    const int4* p = reinterpret_cast<const int4*>(wq);
    int4* o = reinterpret_cast<int4*>(wb);
    for (; i < total16; i += stride) {
        int4 a = p[i * 4], b = p[i * 4 + 1], c = p[i * 4 + 2], d = p[i * 4 + 3];
        int4 v;
        v.x = pack4(a.x - 128, a.y - 128, a.z - 128, a.w - 128);
        v.y = pack4(b.x - 128, b.y - 128, b.z - 128, b.w - 128);
        v.z = pack4(c.x - 128, c.y - 128, c.z - 128, c.w - 128);
        v.w = pack4(d.x - 128, d.y - 128, d.z - 128, d.w - 128);
        o[i] = v;
    }
}

// ------- qgemm: 8-phase i8, 256x128 tile, BKQ=64, 4 waves, 2 blocks/CU -------
// y[t,o] = scale_o*sx_t*S_to + scale_o*(128-zero_o)*rowsum_t + bias_o
//
// r12 with the bfr aliasing bug FIXED: all four B column-halves stay resident
// (bfr[4], indexed bfr[NH*2+n]) exactly as in r9. r12's bfr[2] made P3's
// MFMA_Q(1,0) consume Bh1 instead of Bh0 (absmax 666). FIFO/vmcnt algebra and
// the r7-verified conflict-free swizzle were audited correct and are unchanged.
//
// 4 waves (wave-tile 128x64, acc=128), LDS 2x(A 16KB + B 8KB) = 48KB, 256
// threads -> 2 INDEPENDENT blocks/CU (m114 mechanism: sibling block's MFMA
// covers this block's barrier/vmcnt stalls; single-block lockstep cannot).
//
// Region schedule per 2-tile iteration (A-half stage = 2 loads, B-half = 1):
//   P1 reads Ah0,Bh0(t)   stages Ah1(t+1)->buf1 [2]
//   P2 reads Bh1(t)       stages Ah0(t+2)->buf0 [2]
//   P3 reads Ah1(t)       stages Bh0(t+2)->buf0 [1]
//   P4 reads --           stages Bh1(t+2)->buf0 [1]   VM(4)
//   P5 reads Ah0,Bh0(t+1) stages Ah1(t+2)->buf0 [2]
//   P6 reads Bh1(t+1)     stages Ah0(t+3)->buf1 [2]
//   P7 reads Ah1(t+1)     stages Bh0(t+3)->buf1 [1]
//   P8 reads --           stages Bh1(t+3)->buf1 [1]   VM(4)
// FIFO: 10 outstanding at each wait; VM(4) retires 6 = one full tile
// ({Ah0,Bh0,Bh1,Ah1} of t+1 at P4, of t+2 at P8). Never drains in-loop.

#define LDA_HALF(P, MH)                                                           \
    _Pragma("unroll") for (int m = 0; m < 4; ++m)                                 \
        af[m] = *(const i32x4*)((const char*)&AS[P][0] +                          \
            ((wr * 128 + (MH) * 64 + m * 16 + l15) * 64 +                         \
             ((kq ^ ((l15 >> 1) & 3)) << 4)));

#define LDB_HALF(P, NH)                                                           \
    _Pragma("unroll") for (int n = 0; n < 2; ++n)                                 \
        bfr[(NH) * 2 + n] = *(const i32x4*)((const char*)&BS[P][0] +              \
            ((wc * 64 + (NH) * 32 + n * 16 + l15) * 64 +                          \
             ((kq ^ ((l15 >> 1) & 3)) << 4)));

#define MFMA_Q(MH, NH)                                                            \
    __builtin_amdgcn_s_setprio(1);                                                \
    _Pragma("unroll") for (int m = 0; m < 4; ++m)                                 \
    _Pragma("unroll") for (int n = 0; n < 2; ++n)                                 \
        acc[(MH) * 4 + m][(NH) * 2 + n] = __builtin_amdgcn_mfma_i32_16x16x64_i8(  \
            af[m], bfr[(NH) * 2 + n], acc[(MH) * 4 + m][(NH) * 2 + n], 0, 0, 0);  \
    __builtin_amdgcn_s_setprio(0);

// A tile 16KB = 16 chunks of 1KB (16 rows x 64B). Half H chunks:
// H*4 + (i&3) + (i>>2)*8, i = 2w+j (w=0..3) -> rows {H*64..+63, 128+H*64..+63}
#define STAGE_A(P, H, KT) {                                                       \
    _Pragma("unroll") for (int j = 0; j < 2; ++j) {                               \
        const int i_ = 2 * w + j;                                                 \
        const int chunk = (((H) * 4 + (i_ & 3) + ((i_ >> 2) << 3)) << 10);        \
        const int row_ = (chunk + lane * 16) >> 6;                                \
        const i8* g_ = Abase + (size_t)row_ * IN_F + (KT) * BKQ + sa;             \
        GLOAD_LDS16(g_, (char*)&AS[P][0] + chunk);                                \
    } }

// B tile 8KB = 8 chunks; half H chunks: H*2 + (w&1) + (w>>1)*4, 1 chunk/wave
// -> rows {H*32..+31, 64+H*32..+31}
#define STAGE_B(P, H, KT) {                                                       \
        const int chunk = (((H) * 2 + (w & 1) + ((w >> 1) << 2)) << 10);          \
        const int row_ = (chunk + lane * 16) >> 6;                                \
        const i8* g_ = Bbase + (size_t)row_ * IN_F + (KT) * BKQ + sa;             \
        GLOAD_LDS16(g_, (char*)&BS[P][0] + chunk);                                \
    }

__global__ __launch_bounds__(256, 2) void qgemm_kernel(
    const i8* __restrict__ Xq, const i8* __restrict__ Wqb,
    const float* __restrict__ rowsum, const float* __restrict__ rowscale,
    const float* __restrict__ scale, const float* __restrict__ zero,
    const float* __restrict__ bias, float* __restrict__ out) {
    __shared__ i8 AS[2][BM * BKQ];  // 2 x 16KB
    __shared__ i8 BS[2][BN * BKQ];  // 2 x 8KB   (48KB -> 2 blocks/CU)

    // XCD map: grid = 1376 = 8*172; xcd owns mt in {2x,2x+1}, all nt
    const int bid = blockIdx.x;
    const int xcd = bid & 7;
    const int g   = bid >> 3;            // 0..171
    const int mt  = xcd * 2 + (g & 1);
    const int nt  = g >> 1;              // 0..85

    const int tid  = threadIdx.x;
    const int w    = tid >> 6;        // wave 0..3
    const int lane = tid & 63;
    const int wr   = w >> 1;          // wave row half 0..1 (128 rows each)
    const int wc   = w & 1;           // wave col half 0..1 (64 cols each)
    const int l15  = lane & 15;
    const int kq   = lane >> 4;       // 0..3 (16-elem K slot)
    // stage source swizzle: LDS slot lane&3 at chunk-row lane>>2 holds global
    // slot (lane&3) ^ ((row>>1)&3) = (lane&3) ^ ((lane>>3)&3)  [bytes = elems]
    const int sa = (((lane & 3) ^ ((lane >> 3) & 3)) << 4);

    const i8* Abase = Xq  + (size_t)mt * BM * IN_F;
    const i8* Bbase = Wqb + (size_t)nt * BN * IN_F;

    i32x4 af[4];
    i32x4 bfr[4];
    i32x4 acc[8][4];
    const i32x4 zi = {0, 0, 0, 0};
#pragma unroll
    for (int m = 0; m < 8; ++m)
#pragma unroll
        for (int n = 0; n < 4; ++n) acc[m][n] = zi;

    // ---- prologue: tiles 0,1 staged in FIFO order (10 loads) ----
    STAGE_A(0, 0, 0);   // Ah0(0) [2]
    STAGE_B(0, 0, 0);   // Bh0(0) [1]
    STAGE_B(0, 1, 0);   // Bh1(0) [1]
    STAGE_A(0, 1, 0);   // Ah1(0) [2]
    STAGE_A(1, 0, 1);   // Ah0(1) [2]
    STAGE_B(1, 0, 1);   // Bh0(1) [1]
    STAGE_B(1, 1, 1);   // Bh1(1) [1]
    VM(4);              // retires tile 0 (6 loads); 4 remain
    BAR();

    // ---- steady loop: 31 iterations, tiles 0..61 (stages through 63) ----
    for (int i = 0; i < 31; ++i) {
        const int t = 2 * i;
        // P1
        LDA_HALF(0, 0); LDB_HALF(0, 0);
        STAGE_A(1, 1, t + 1);
        BAR();
        MFMA_Q(0, 0);
        BAR();
        // P2
        LDB_HALF(0, 1);
        STAGE_A(0, 0, t + 2);
        BAR();
        MFMA_Q(0, 1);
        BAR();
        // P3
        LDA_HALF(0, 1);
        STAGE_B(0, 0, t + 2);
        BAR();
        MFMA_Q(1, 0);
        BAR();
        // P4
        STAGE_B(0, 1, t + 2);
        BAR();
        MFMA_Q(1, 1);
        VM(4); BAR();   // retires {Ah0,Bh0,Bh1,Ah1}(t+1) -> covers P5-P7
        // P5
        LDA_HALF(1, 0); LDB_HALF(1, 0);
        STAGE_A(0, 1, t + 2);
        BAR();
        MFMA_Q(0, 0);
        BAR();
        // P6
        LDB_HALF(1, 1);
        STAGE_A(1, 0, t + 3);
        BAR();
        MFMA_Q(0, 1);
        BAR();
        // P7
        LDA_HALF(1, 1);
        STAGE_B(1, 0, t + 3);
        BAR();
        MFMA_Q(1, 0);
        BAR();
        // P8
        STAGE_B(1, 1, t + 3);
        BAR();
        MFMA_Q(1, 1);
        VM(4); BAR();   // retires {Ah0,Bh0,Bh1,Ah1}(t+2) -> covers next P1-P3
    }

    // ---- peeled final iteration: tiles 62 (buf0), 63 (buf1) ----
    // P1
    LDA_HALF(0, 0); LDB_HALF(0, 0);
    STAGE_A(1, 1, 63);
    BAR();
    MFMA_Q(0, 0);
    BAR();
    // P2
    LDB_HALF(0, 1);
    BAR();
    MFMA_Q(0, 1);
    BAR();
    // P3
    LDA_HALF(0, 1);
    BAR();
    MFMA_Q(1, 0);
    BAR();
    // P4
    BAR();
    MFMA_Q(1, 1);
    VM(0); BAR();   // drain: all tile-63 stages landed
    // P5
    LDA_HALF(1, 0); LDB_HALF(1, 0);
    BAR();
    MFMA_Q(0, 0);
    BAR();
    // P6
    LDB_HALF(1, 1);
    BAR();
    MFMA_Q(0, 1);
    BAR();
    // P7
    LDA_HALF(1, 1);
    BAR();
    MFMA_Q(1, 0);
    BAR();
    // P8
    BAR();
    MFMA_Q(1, 1);

    // ---- epilogue: C/D layout col = lane&15, row = (lane>>4)*4 + j ----
    // y = scale*sx*S + scale*(128-zero)*rowsum + bias
    const int rowt = mt * BM + wr * 128;
    const int colt = nt * BN + wc * 64;

    float scn[4], bcn[4], ccn[4];
#pragma unroll
    for (int n = 0; n < 4; ++n) {
        const int col = colt + n * 16 + l15;
        scn[n] = scale[col];
        bcn[n] = scn[n] * (128.0f - zero[col]);
        ccn[n] = bias[col];
    }
#pragma unroll
    for (int m = 0; m < 8; ++m) {
#pragma unroll
        for (int j = 0; j < 4; ++j) {
            const int r = rowt + m * 16 + kq * 4 + j;
            const float rsv = rowsum[r];
            const float sxv = rowscale[r];
#pragma unroll
            for (int n = 0; n < 4; ++n) {
                out[(size_t)r * OUT_F + colt + n * 16 + l15] =
                    scn[n] * (sxv * (float)acc[m][n][j]) + bcn[n] * rsv + ccn[n];
            }
        }
    }
}

extern "C" void kernel_launch(void* const* d_in, const int* in_sizes, int n_in,
                              void* d_out, int out_size, void* d_ws, size_t ws_size,
                              hipStream_t stream) {
    const float* x     = (const float*)d_in[0];
    const int*   wq    = (const int*)d_in[1];
    const float* scale = (const float*)d_in[2];
    const float* zero  = (const float*)d_in[3];
    const float* bias  = (const float*)d_in[4];
    float* out = (float*)d_out;

    // workspace: Wq' i8 (45.1 MB) | Xq i8 (16.8 MB) | rowsum (16 KB) | rowscale (16 KB)
    char* ws = (char*)d_ws;
    i8* Wqb = (i8*)ws;
    i8* Xq  = (i8*)(ws + (size_t)OUT_F * IN_F);
    float* rowsum   = (float*)(ws + (size_t)OUT_F * IN_F + (size_t)TOKENS * IN_F);
    float* rowscale = rowsum + TOKENS;

    prep_w_kernel<<<2048, 256, 0, stream>>>(wq, Wqb);
    prep_x_kernel<<<TOKENS, 256, 0, stream>>>(x, Xq, rowsum, rowscale);
    qgemm_kernel<<<MT * NT, 256, 0, stream>>>(Xq, Wqb, rowsum, rowscale,
                                              scale, zero, bias, out);
}

// Round 14
// 243.153 us; speedup vs baseline: 1.0952x; 1.0855x over previous
//
#include <hip/hip_runtime.h>

typedef unsigned short u16;
typedef unsigned int   u32;
typedef unsigned long long u64;
typedef signed char    i8;

typedef int   i32x4 __attribute__((ext_vector_type(4)));

#define IN_F   4096
#define OUT_F  11008
#define TOKENS 4096

#define BM 256
#define BN 256
#define BKQ 128              // K per tile in i8 elems = 128B rows
#define MT (TOKENS / BM)     // 16
#define NT (OUT_F / BN)      // 43
#define KTILES (IN_F / BKQ)  // 32

// direct global->LDS async copy, 16B per lane; LDS dest = wave-uniform base + lane*16
#define GLOAD_LDS16(g, l)                                                        \
    __builtin_amdgcn_global_load_lds(                                            \
        (const __attribute__((address_space(1))) u32*)(u64)(g),                  \
        (__attribute__((address_space(3))) u32*)(u64)(l), 16, 0, 0)

#define BAR() __builtin_amdgcn_s_barrier()
#define VM(N)    asm volatile("s_waitcnt vmcnt(" #N ")" ::: "memory")
#define LGKM(N)  asm volatile("s_waitcnt lgkmcnt(" #N ")" ::: "memory")

__device__ __forceinline__ int pack4(int a, int b, int c, int d) {
    return (a & 255) | ((b & 255) << 8) | ((c & 255) << 16) | (d << 24);
}

// ------- prep_x: f32 -> i8 per-row symmetric quant + exact f32 rowsum --------
__global__ __launch_bounds__(256) void prep_x_kernel(
    const float* __restrict__ x, i8* __restrict__ xq,
    float* __restrict__ rowsum, float* __restrict__ rowscale) {
    const int row = blockIdx.x;
    const int tid = threadIdx.x;
    const float4* xr = reinterpret_cast<const float4*>(x + (size_t)row * IN_F);
    float4 v[4];
    float s = 0.f, mx = 0.f;
#pragma unroll
    for (int i = 0; i < 4; ++i) {
        v[i] = xr[tid * 4 + i];
        s += v[i].x + v[i].y + v[i].z + v[i].w;
        mx = fmaxf(mx, fmaxf(fmaxf(fabsf(v[i].x), fabsf(v[i].y)),
                             fmaxf(fabsf(v[i].z), fabsf(v[i].w))));
    }
#pragma unroll
    for (int off = 32; off > 0; off >>= 1) {
        s += __shfl_down(s, off, 64);
        mx = fmaxf(mx, __shfl_down(mx, off, 64));
    }
    __shared__ float ss[4], sm[4];
    if ((tid & 63) == 0) { ss[tid >> 6] = s; sm[tid >> 6] = mx; }
    __syncthreads();
    const float tot = ss[0] + ss[1] + ss[2] + ss[3];
    const float m4  = fmaxf(fmaxf(sm[0], sm[1]), fmaxf(sm[2], sm[3]));
    const float mg  = fmaxf(m4, 1e-20f);
    const float inv = 127.0f / mg;
    if (tid == 0) { rowsum[row] = tot; rowscale[row] = mg * (1.0f / 127.0f); }
    int4 o;
    int q[16];
#pragma unroll
    for (int i = 0; i < 4; ++i) {
        q[4 * i + 0] = (int)rintf(v[i].x * inv);
        q[4 * i + 1] = (int)rintf(v[i].y * inv);
        q[4 * i + 2] = (int)rintf(v[i].z * inv);
        q[4 * i + 3] = (int)rintf(v[i].w * inv);
    }
    o.x = pack4(q[0], q[1], q[2], q[3]);
    o.y = pack4(q[4], q[5], q[6], q[7]);
    o.z = pack4(q[8], q[9], q[10], q[11]);
    o.w = pack4(q[12], q[13], q[14], q[15]);
    reinterpret_cast<int4*>(xq + (size_t)row * IN_F)[tid] = o;
}

// ---------------- prep_w: int32 (0..255) -> i8 (wq - 128, exact) ----------------
__global__ __launch_bounds__(256) void prep_w_kernel(
    const int* __restrict__ wq, i8* __restrict__ wb) {
    const size_t total16 = (size_t)OUT_F * IN_F / 16;
    size_t i = (size_t)blockIdx.x * blockDim.x + threadIdx.x;
    const size_t stride = (size_t)gridDim.x * blockDim.x;
    const int4* p = reinterpret_cast<const int4*>(wq);
    int4* o = reinterpret_cast<int4*>(wb);
    for (; i < total16; i += stride) {
        int4 a = p[i * 4], b = p[i * 4 + 1], c = p[i * 4 + 2], d = p[i * 4 + 3];
        int4 v;
        v.x = pack4(a.x - 128, a.y - 128, a.z - 128, a.w - 128);
        v.y = pack4(b.x - 128, b.y - 128, b.z - 128, b.w - 128);
        v.z = pack4(c.x - 128, c.y - 128, c.z - 128, c.w - 128);
        v.w = pack4(d.x - 128, d.y - 128, d.z - 128, d.w - 128);
        o[i] = v;
    }
}

// ------- qgemm: champion r10 (8-phase i8, 256x256, VM(6)@P4/P8) + micro-opts --
// y[t,o] = scale_o*sx_t*S_to + scale_o*(128-zero_o)*rowsum_t + bias_o
// Changes vs r10: (1) nontemporal epilogue stores (out is write-once; keep L2
// for A/B panels); (2) epilogue constants (scale/zero/bias) hoisted above the
// K-loop so their load latency hides under the loop. Schedule, swizzle
// (conflicts=0), vmcnt algebra, XCD map all byte-identical to r10.

#define LDA_HALF(P, MH)                                                           \
    _Pragma("unroll") for (int m = 0; m < 4; ++m)                                 \
    _Pragma("unroll") for (int s = 0; s < 2; ++s)                                 \
        af[m][s] = *(const i32x4*)((const char*)&AS[P][0] +                       \
            ((wr * 128 + (MH) * 64 + m * 16 + l15) * 128 +                        \
             (((s * 4 + kq) ^ (l15 & 7)) << 4)));

#define LDB_HALF(P, NH)                                                           \
    _Pragma("unroll") for (int n = 0; n < 2; ++n)                                 \
    _Pragma("unroll") for (int s = 0; s < 2; ++s)                                 \
        bfr[(NH) * 2 + n][s] = *(const i32x4*)((const char*)&BS[P][0] +           \
            ((wc * 64 + (NH) * 32 + n * 16 + l15) * 128 +                         \
             (((s * 4 + kq) ^ (l15 & 7)) << 4)));

#define MFMA_Q(MH, NH)                                                            \
    __builtin_amdgcn_s_setprio(1);                                                \
    _Pragma("unroll") for (int m = 0; m < 4; ++m)                                 \
    _Pragma("unroll") for (int n = 0; n < 2; ++n)                                 \
    _Pragma("unroll") for (int s = 0; s < 2; ++s)                                 \
        acc[(MH) * 4 + m][(NH) * 2 + n] = __builtin_amdgcn_mfma_i32_16x16x64_i8(  \
            af[m][s], bfr[(NH) * 2 + n][s], acc[(MH) * 4 + m][(NH) * 2 + n],      \
            0, 0, 0);                                                             \
    __builtin_amdgcn_s_setprio(0);

// A half-region H of k-tile KT into buf P: 16 chunks of 1KB, 2/wave.
#define STAGE_A(P, H, KT) {                                                       \
    _Pragma("unroll") for (int j = 0; j < 2; ++j) {                               \
        const int i_ = 2 * w + j;                                                 \
        const int chunk = (((H) * 8 + (i_ & 7) + ((i_ >> 3) << 4)) << 10);        \
        const int row_ = (chunk + lane * 16) >> 7;                                \
        const int cb_ = (((lane & 7) ^ (row_ & 7)) << 4);                         \
        const i8* g_ = Abase + (size_t)row_ * IN_F + (KT) * BKQ + cb_;            \
        GLOAD_LDS16(g_, (char*)&AS[P][0] + chunk);                                \
    } }

// B half-region H: chunk = H*4 + (i&3) + (i>>2)*8
#define STAGE_B(P, H, KT) {                                                       \
    _Pragma("unroll") for (int j = 0; j < 2; ++j) {                               \
        const int i_ = 2 * w + j;                                                 \
        const int chunk = (((H) * 4 + (i_ & 3) + ((i_ >> 2) << 3)) << 10);        \
        const int row_ = (chunk + lane * 16) >> 7;                                \
        const int cb_ = (((lane & 7) ^ (row_ & 7)) << 4);                         \
        const i8* g_ = Bbase + (size_t)row_ * IN_F + (KT) * BKQ + cb_;            \
        GLOAD_LDS16(g_, (char*)&BS[P][0] + chunk);                                \
    } }

__global__ __launch_bounds__(512, 1) void qgemm_kernel(
    const i8* __restrict__ Xq, const i8* __restrict__ Wqb,
    const float* __restrict__ rowsum, const float* __restrict__ rowscale,
    const float* __restrict__ scale, const float* __restrict__ zero,
    const float* __restrict__ bias, float* __restrict__ out) {
    __shared__ i8 AS[2][BM * BKQ];  // 2 x 32KB
    __shared__ i8 BS[2][BN * BKQ];  // 2 x 32KB

    // XCD map: xcd owns 2mt x 43nt
    const int bid = blockIdx.x;
    const int xcd = bid & 7;
    const int g   = bid >> 3;            // 0..85
    const int mt  = xcd * 2 + (g & 1);
    const int nt  = g >> 1;

    const int tid  = threadIdx.x;
    const int w    = tid >> 6;        // wave 0..7
    const int lane = tid & 63;
    const int wr   = w >> 2;          // wave row half 0..1 (128 rows each)
    const int wc   = w & 3;           // wave col 0..3 (64 cols each)
    const int l15  = lane & 15;
    const int kq   = lane >> 4;       // 0..3 (16-elem K slot within 64)

    const i8* Abase = Xq  + (size_t)mt * BM * IN_F;
    const i8* Bbase = Wqb + (size_t)nt * BN * IN_F;

    // hoisted epilogue constants: latency hides under the K-loop
    const int rowt = mt * BM + wr * 128;
    const int colt = nt * BN + wc * 64;
    float scn[4], bcn[4], ccn[4];
#pragma unroll
    for (int n = 0; n < 4; ++n) {
        const int col = colt + n * 16 + l15;
        scn[n] = scale[col];
        bcn[n] = scn[n] * (128.0f - zero[col]);
        ccn[n] = bias[col];
    }

    i32x4 af[4][2];
    i32x4 bfr[4][2];
    i32x4 acc[8][4];
    const i32x4 zi = {0, 0, 0, 0};
#pragma unroll
    for (int m = 0; m < 8; ++m)
#pragma unroll
        for (int n = 0; n < 4; ++n) acc[m][n] = zi;

    // ---- prologue: 7 half-stages in steady-state FIFO order ----
    STAGE_A(0, 0, 0);   // Ah0(0)
    STAGE_B(0, 0, 0);   // Bh0(0)
    STAGE_B(0, 1, 0);   // Bh1(0)
    STAGE_A(0, 1, 0);   // Ah1(0)
    STAGE_A(1, 0, 1);   // Ah0(1)
    STAGE_B(1, 0, 1);   // Bh0(1)
    STAGE_B(1, 1, 1);   // Bh1(1)
    VM(6);              // retires ALL of tile 0 (covers P1-P3 reads)
    BAR();

    // ---- steady loop: 15 iterations, tiles 0..29 (stages through 31) ----
    for (int i = 0; i < 15; ++i) {
        const int t = 2 * i;
        // P1
        LDA_HALF(0, 0); LDB_HALF(0, 0);
        STAGE_A(1, 1, t + 1);
        LGKM(8);
        BAR();
        LGKM(0);
        MFMA_Q(0, 0);
        BAR();
        // P2
        LDB_HALF(0, 1);
        STAGE_A(0, 0, t + 2);
        BAR();
        LGKM(0);
        MFMA_Q(0, 1);
        BAR();
        // P3
        LDA_HALF(0, 1);
        STAGE_B(0, 0, t + 2);
        BAR();
        LGKM(0);
        MFMA_Q(1, 0);
        BAR();
        // P4
        STAGE_B(0, 1, t + 2);
        BAR();
        MFMA_Q(1, 1);
        VM(6); BAR();   // retires {Ah0,Bh0,Bh1,Ah1}(t+1) -> covers P5-P7
        // P5
        LDA_HALF(1, 0); LDB_HALF(1, 0);
        STAGE_A(0, 1, t + 2);
        LGKM(8);
        BAR();
        LGKM(0);
        MFMA_Q(0, 0);
        BAR();
        // P6
        LDB_HALF(1, 1);
        STAGE_A(1, 0, t + 3);
        BAR();
        LGKM(0);
        MFMA_Q(0, 1);
        BAR();
        // P7
        LDA_HALF(1, 1);
        STAGE_B(1, 0, t + 3);
        BAR();
        LGKM(0);
        MFMA_Q(1, 0);
        BAR();
        // P8
        STAGE_B(1, 1, t + 3);
        BAR();
        MFMA_Q(1, 1);
        VM(6); BAR();   // retires {Ah0,Bh0,Bh1,Ah1}(t+2) -> covers next P1-P3
    }

    // ---- peeled final iteration: tiles 30 (buf0), 31 (buf1) ----
    // P1
    LDA_HALF(0, 0); LDB_HALF(0, 0);
    STAGE_A(1, 1, 31);
    BAR();
    LGKM(0);
    MFMA_Q(0, 0);
    BAR();
    // P2
    LDB_HALF(0, 1);
    BAR();
    LGKM(0);
    MFMA_Q(0, 1);
    BAR();
    // P3
    LDA_HALF(0, 1);
    BAR();
    LGKM(0);
    MFMA_Q(1, 0);
    BAR();
    // P4
    BAR();
    MFMA_Q(1, 1);
    VM(0); BAR();   // drain: all tile-31 stages landed
    // P5
    LDA_HALF(1, 0); LDB_HALF(1, 0);
    BAR();
    LGKM(0);
    MFMA_Q(0, 0);
    BAR();
    // P6
    LDB_HALF(1, 1);
    BAR();
    LGKM(0);
    MFMA_Q(0, 1);
    BAR();
    // P7
    LDA_HALF(1, 1);
    BAR();
    LGKM(0);
    MFMA_Q(1, 0);
    BAR();
    // P8
    BAR();
    MFMA_Q(1, 1);

    // ---- epilogue: C/D layout col = lane&15, row = (lane>>4)*4 + j ----
    // y = scale*sx*S + scale*(128-zero)*rowsum + bias ; nontemporal stores
#pragma unroll
    for (int m = 0; m < 8; ++m) {
#pragma unroll
        for (int j = 0; j < 4; ++j) {
            const int r = rowt + m * 16 + kq * 4 + j;
            const float rsv = rowsum[r];
            const float sxv = rowscale[r];
#pragma unroll
            for (int n = 0; n < 4; ++n) {
                __builtin_nontemporal_store(
                    scn[n] * (sxv * (float)acc[m][n][j]) + bcn[n] * rsv + ccn[n],
                    &out[(size_t)r * OUT_F + colt + n * 16 + l15]);
            }
        }
    }
}

extern "C" void kernel_launch(void* const* d_in, const int* in_sizes, int n_in,
                              void* d_out, int out_size, void* d_ws, size_t ws_size,
                              hipStream_t stream) {
    const float* x     = (const float*)d_in[0];
    const int*   wq    = (const int*)d_in[1];
    const float* scale = (const float*)d_in[2];
    const float* zero  = (const float*)d_in[3];
    const float* bias  = (const float*)d_in[4];
    float* out = (float*)d_out;

    // workspace: Wq' i8 (45.1 MB) | Xq i8 (16.8 MB) | rowsum (16 KB) | rowscale (16 KB)
    char* ws = (char*)d_ws;
    i8* Wqb = (i8*)ws;
    i8* Xq  = (i8*)(ws + (size_t)OUT_F * IN_F);
    float* rowsum   = (float*)(ws + (size_t)OUT_F * IN_F + (size_t)TOKENS * IN_F);
    float* rowscale = rowsum + TOKENS;

    prep_w_kernel<<<2048, 256, 0, stream>>>(wq, Wqb);
    prep_x_kernel<<<TOKENS, 256, 0, stream>>>(x, Xq, rowsum, rowscale);
    qgemm_kernel<<<MT * NT, 512, 0, stream>>>(Xq, Wqb, rowsum, rowscale,
                                              scale, zero, bias, out);
}

// Round 15
// 239.922 us; speedup vs baseline: 1.1100x; 1.0135x over previous
//
#include <hip/hip_runtime.h>

typedef unsigned short u16;
typedef unsigned int   u32;
typedef unsigned long long u64;
typedef signed char    i8;

typedef int   i32x4 __attribute__((ext_vector_type(4)));

#define IN_F   4096
#define OUT_F  11008
#define TOKENS 4096

#define BM 256
#define BN 256
#define BKQ 128              // K per tile in i8 elems = 128B rows
#define MT (TOKENS / BM)     // 16
#define NT (OUT_F / BN)      // 43
#define KTILES (IN_F / BKQ)  // 32

// direct global->LDS async copy, 16B per lane; LDS dest = wave-uniform base + lane*16
#define GLOAD_LDS16(g, l)                                                        \
    __builtin_amdgcn_global_load_lds(                                            \
        (const __attribute__((address_space(1))) u32*)(u64)(g),                  \
        (__attribute__((address_space(3))) u32*)(u64)(l), 16, 0, 0)

#define BAR() __builtin_amdgcn_s_barrier()
#define VM(N)    asm volatile("s_waitcnt vmcnt(" #N ")" ::: "memory")
#define LGKM(N)  asm volatile("s_waitcnt lgkmcnt(" #N ")" ::: "memory")

__device__ __forceinline__ int pack4(int a, int b, int c, int d) {
    return (a & 255) | ((b & 255) << 8) | ((c & 255) << 16) | (d << 24);
}

// ------- prep_x: f32 -> i8 per-row symmetric quant + exact f32 rowsum --------
__global__ __launch_bounds__(256) void prep_x_kernel(
    const float* __restrict__ x, i8* __restrict__ xq,
    float* __restrict__ rowsum, float* __restrict__ rowscale) {
    const int row = blockIdx.x;
    const int tid = threadIdx.x;
    const float4* xr = reinterpret_cast<const float4*>(x + (size_t)row * IN_F);
    float4 v[4];
    float s = 0.f, mx = 0.f;
#pragma unroll
    for (int i = 0; i < 4; ++i) {
        v[i] = xr[tid * 4 + i];
        s += v[i].x + v[i].y + v[i].z + v[i].w;
        mx = fmaxf(mx, fmaxf(fmaxf(fabsf(v[i].x), fabsf(v[i].y)),
                             fmaxf(fabsf(v[i].z), fabsf(v[i].w))));
    }
#pragma unroll
    for (int off = 32; off > 0; off >>= 1) {
        s += __shfl_down(s, off, 64);
        mx = fmaxf(mx, __shfl_down(mx, off, 64));
    }
    __shared__ float ss[4], sm[4];
    if ((tid & 63) == 0) { ss[tid >> 6] = s; sm[tid >> 6] = mx; }
    __syncthreads();
    const float tot = ss[0] + ss[1] + ss[2] + ss[3];
    const float m4  = fmaxf(fmaxf(sm[0], sm[1]), fmaxf(sm[2], sm[3]));
    const float mg  = fmaxf(m4, 1e-20f);
    const float inv = 127.0f / mg;
    if (tid == 0) { rowsum[row] = tot; rowscale[row] = mg * (1.0f / 127.0f); }
    int4 o;
    int q[16];
#pragma unroll
    for (int i = 0; i < 4; ++i) {
        q[4 * i + 0] = (int)rintf(v[i].x * inv);
        q[4 * i + 1] = (int)rintf(v[i].y * inv);
        q[4 * i + 2] = (int)rintf(v[i].z * inv);
        q[4 * i + 3] = (int)rintf(v[i].w * inv);
    }
    o.x = pack4(q[0], q[1], q[2], q[3]);
    o.y = pack4(q[4], q[5], q[6], q[7]);
    o.z = pack4(q[8], q[9], q[10], q[11]);
    o.w = pack4(q[12], q[13], q[14], q[15]);
    reinterpret_cast<int4*>(xq + (size_t)row * IN_F)[tid] = o;
}

// ---------------- prep_w: int32 (0..255) -> i8 (wq - 128, exact) ----------------
__global__ __launch_bounds__(256) void prep_w_kernel(
    const int* __restrict__ wq, i8* __restrict__ wb) {
    const size_t total16 = (size_t)OUT_F * IN_F / 16;
    size_t i = (size_t)blockIdx.x * blockDim.x + threadIdx.x;
    const size_t stride = (size_t)gridDim.x * blockDim.x;
    const int4* p = reinterpret_cast<const int4*>(wq);
    int4* o = reinterpret_cast<int4*>(wb);
    for (; i < total16; i += stride) {
        int4 a = p[i * 4], b = p[i * 4 + 1], c = p[i * 4 + 2], d = p[i * 4 + 3];
        int4 v;
        v.x = pack4(a.x - 128, a.y - 128, a.z - 128, a.w - 128);
        v.y = pack4(b.x - 128, b.y - 128, b.z - 128, b.w - 128);
        v.z = pack4(c.x - 128, c.y - 128, c.z - 128, c.w - 128);
        v.w = pack4(d.x - 128, d.y - 128, d.z - 128, d.w - 128);
        o[i] = v;
    }
}

// ------- qgemm: champion r10 restored byte-exact (8-phase i8, 256x256) -------
// y[t,o] = scale_o*sx_t*S_to + scale_o*(128-zero_o)*rowsum_t + bias_o
// S_to = sum_k xq[t,k]*wq'[o,k]  (exact i32 via mfma_i32_16x16x64_i8)
//
// Measured local optimum: every one-variable neighbor is worse —
//   wait frequency (r10 vs r9: null), 32x32 shape (r11: -15%, conflicts),
//   2 blocks/CU smaller tile (r13: -13%), coarse phases (r8: -50%),
//   NT stores + hoisted epilogue consts (r14: -12%, WRITE_SIZE +31%).
// 256x256 tile, BKQ=128 (128B rows), 8 waves (2Mx4N, 128x64/wave),
// LDS 2x(32K+32K)=128KB, 1 block/CU. Swizzle conflicts=0; VM(6)@P4/P8 only;
// lgkm hints; setprio around MFMA; XCD map 2mt x 43nt (FETCH 201MB).

#define LDA_HALF(P, MH)                                                           \
    _Pragma("unroll") for (int m = 0; m < 4; ++m)                                 \
    _Pragma("unroll") for (int s = 0; s < 2; ++s)                                 \
        af[m][s] = *(const i32x4*)((const char*)&AS[P][0] +                       \
            ((wr * 128 + (MH) * 64 + m * 16 + l15) * 128 +                        \
             (((s * 4 + kq) ^ (l15 & 7)) << 4)));

#define LDB_HALF(P, NH)                                                           \
    _Pragma("unroll") for (int n = 0; n < 2; ++n)                                 \
    _Pragma("unroll") for (int s = 0; s < 2; ++s)                                 \
        bfr[(NH) * 2 + n][s] = *(const i32x4*)((const char*)&BS[P][0] +           \
            ((wc * 64 + (NH) * 32 + n * 16 + l15) * 128 +                         \
             (((s * 4 + kq) ^ (l15 & 7)) << 4)));

#define MFMA_Q(MH, NH)                                                            \
    __builtin_amdgcn_s_setprio(1);                                                \
    _Pragma("unroll") for (int m = 0; m < 4; ++m)                                 \
    _Pragma("unroll") for (int n = 0; n < 2; ++n)                                 \
    _Pragma("unroll") for (int s = 0; s < 2; ++s)                                 \
        acc[(MH) * 4 + m][(NH) * 2 + n] = __builtin_amdgcn_mfma_i32_16x16x64_i8(  \
            af[m][s], bfr[(NH) * 2 + n][s], acc[(MH) * 4 + m][(NH) * 2 + n],      \
            0, 0, 0);                                                             \
    __builtin_amdgcn_s_setprio(0);

// A half-region H of k-tile KT into buf P: 16 chunks of 1KB, 2/wave.
#define STAGE_A(P, H, KT) {                                                       \
    _Pragma("unroll") for (int j = 0; j < 2; ++j) {                               \
        const int i_ = 2 * w + j;                                                 \
        const int chunk = (((H) * 8 + (i_ & 7) + ((i_ >> 3) << 4)) << 10);        \
        const int row_ = (chunk + lane * 16) >> 7;                                \
        const int cb_ = (((lane & 7) ^ (row_ & 7)) << 4);                         \
        const i8* g_ = Abase + (size_t)row_ * IN_F + (KT) * BKQ + cb_;            \
        GLOAD_LDS16(g_, (char*)&AS[P][0] + chunk);                                \
    } }

// B half-region H: chunk = H*4 + (i&3) + (i>>2)*8
#define STAGE_B(P, H, KT) {                                                       \
    _Pragma("unroll") for (int j = 0; j < 2; ++j) {                               \
        const int i_ = 2 * w + j;                                                 \
        const int chunk = (((H) * 4 + (i_ & 3) + ((i_ >> 2) << 3)) << 10);        \
        const int row_ = (chunk + lane * 16) >> 7;                                \
        const int cb_ = (((lane & 7) ^ (row_ & 7)) << 4);                         \
        const i8* g_ = Bbase + (size_t)row_ * IN_F + (KT) * BKQ + cb_;            \
        GLOAD_LDS16(g_, (char*)&BS[P][0] + chunk);                                \
    } }

__global__ __launch_bounds__(512, 1) void qgemm_kernel(
    const i8* __restrict__ Xq, const i8* __restrict__ Wqb,
    const float* __restrict__ rowsum, const float* __restrict__ rowscale,
    const float* __restrict__ scale, const float* __restrict__ zero,
    const float* __restrict__ bias, float* __restrict__ out) {
    __shared__ i8 AS[2][BM * BKQ];  // 2 x 32KB
    __shared__ i8 BS[2][BN * BKQ];  // 2 x 32KB

    // XCD map: xcd owns 2mt x 43nt
    const int bid = blockIdx.x;
    const int xcd = bid & 7;
    const int g   = bid >> 3;            // 0..85
    const int mt  = xcd * 2 + (g & 1);
    const int nt  = g >> 1;

    const int tid  = threadIdx.x;
    const int w    = tid >> 6;        // wave 0..7
    const int lane = tid & 63;
    const int wr   = w >> 2;          // wave row half 0..1 (128 rows each)
    const int wc   = w & 3;           // wave col 0..3 (64 cols each)
    const int l15  = lane & 15;
    const int kq   = lane >> 4;       // 0..3 (16-elem K slot within 64)

    const i8* Abase = Xq  + (size_t)mt * BM * IN_F;
    const i8* Bbase = Wqb + (size_t)nt * BN * IN_F;

    i32x4 af[4][2];
    i32x4 bfr[4][2];
    i32x4 acc[8][4];
    const i32x4 zi = {0, 0, 0, 0};
#pragma unroll
    for (int m = 0; m < 8; ++m)
#pragma unroll
        for (int n = 0; n < 4; ++n) acc[m][n] = zi;

    // ---- prologue: 7 half-stages in steady-state FIFO order ----
    STAGE_A(0, 0, 0);   // Ah0(0)
    STAGE_B(0, 0, 0);   // Bh0(0)
    STAGE_B(0, 1, 0);   // Bh1(0)
    STAGE_A(0, 1, 0);   // Ah1(0)
    STAGE_A(1, 0, 1);   // Ah0(1)
    STAGE_B(1, 0, 1);   // Bh0(1)
    STAGE_B(1, 1, 1);   // Bh1(1)
    VM(6);              // retires ALL of tile 0 (covers P1-P3 reads)
    BAR();

    // ---- steady loop: 15 iterations, tiles 0..29 (stages through 31) ----
    for (int i = 0; i < 15; ++i) {
        const int t = 2 * i;
        // P1
        LDA_HALF(0, 0); LDB_HALF(0, 0);
        STAGE_A(1, 1, t + 1);
        LGKM(8);
        BAR();
        LGKM(0);
        MFMA_Q(0, 0);
        BAR();
        // P2
        LDB_HALF(0, 1);
        STAGE_A(0, 0, t + 2);
        BAR();
        LGKM(0);
        MFMA_Q(0, 1);
        BAR();
        // P3
        LDA_HALF(0, 1);
        STAGE_B(0, 0, t + 2);
        BAR();
        LGKM(0);
        MFMA_Q(1, 0);
        BAR();
        // P4
        STAGE_B(0, 1, t + 2);
        BAR();
        MFMA_Q(1, 1);
        VM(6); BAR();   // retires {Ah0,Bh0,Bh1,Ah1}(t+1) -> covers P5-P7
        // P5
        LDA_HALF(1, 0); LDB_HALF(1, 0);
        STAGE_A(0, 1, t + 2);
        LGKM(8);
        BAR();
        LGKM(0);
        MFMA_Q(0, 0);
        BAR();
        // P6
        LDB_HALF(1, 1);
        STAGE_A(1, 0, t + 3);
        BAR();
        LGKM(0);
        MFMA_Q(0, 1);
        BAR();
        // P7
        LDA_HALF(1, 1);
        STAGE_B(1, 0, t + 3);
        BAR();
        LGKM(0);
        MFMA_Q(1, 0);
        BAR();
        // P8
        STAGE_B(1, 1, t + 3);
        BAR();
        MFMA_Q(1, 1);
        VM(6); BAR();   // retires {Ah0,Bh0,Bh1,Ah1}(t+2) -> covers next P1-P3
    }

    // ---- peeled final iteration: tiles 30 (buf0), 31 (buf1) ----
    // P1
    LDA_HALF(0, 0); LDB_HALF(0, 0);
    STAGE_A(1, 1, 31);
    BAR();
    LGKM(0);
    MFMA_Q(0, 0);
    BAR();
    // P2
    LDB_HALF(0, 1);
    BAR();
    LGKM(0);
    MFMA_Q(0, 1);
    BAR();
    // P3
    LDA_HALF(0, 1);
    BAR();
    LGKM(0);
    MFMA_Q(1, 0);
    BAR();
    // P4
    BAR();
    MFMA_Q(1, 1);
    VM(0); BAR();   // drain: all tile-31 stages landed
    // P5
    LDA_HALF(1, 0); LDB_HALF(1, 0);
    BAR();
    LGKM(0);
    MFMA_Q(0, 0);
    BAR();
    // P6
    LDB_HALF(1, 1);
    BAR();
    LGKM(0);
    MFMA_Q(0, 1);
    BAR();
    // P7
    LDA_HALF(1, 1);
    BAR();
    LGKM(0);
    MFMA_Q(1, 0);
    BAR();
    // P8
    BAR();
    MFMA_Q(1, 1);

    // ---- epilogue: C/D layout col = lane&15, row = (lane>>4)*4 + j ----
    // y = scale*sx*S + scale*(128-zero)*rowsum + bias
    const int rowt = mt * BM + wr * 128;
    const int colt = nt * BN + wc * 64;

    float scn[4], bcn[4], ccn[4];
#pragma unroll
    for (int n = 0; n < 4; ++n) {
        const int col = colt + n * 16 + l15;
        scn[n] = scale[col];
        bcn[n] = scn[n] * (128.0f - zero[col]);
        ccn[n] = bias[col];
    }
#pragma unroll
    for (int m = 0; m < 8; ++m) {
#pragma unroll
        for (int j = 0; j < 4; ++j) {
            const int r = rowt + m * 16 + kq * 4 + j;
            const float rsv = rowsum[r];
            const float sxv = rowscale[r];
#pragma unroll
            for (int n = 0; n < 4; ++n) {
                out[(size_t)r * OUT_F + colt + n * 16 + l15] =
                    scn[n] * (sxv * (float)acc[m][n][j]) + bcn[n] * rsv + ccn[n];
            }
        }
    }
}

extern "C" void kernel_launch(void* const* d_in, const int* in_sizes, int n_in,
                              void* d_out, int out_size, void* d_ws, size_t ws_size,
                              hipStream_t stream) {
    const float* x     = (const float*)d_in[0];
    const int*   wq    = (const int*)d_in[1];
    const float* scale = (const float*)d_in[2];
    const float* zero  = (const float*)d_in[3];
    const float* bias  = (const float*)d_in[4];
    float* out = (float*)d_out;

    // workspace: Wq' i8 (45.1 MB) | Xq i8 (16.8 MB) | rowsum (16 KB) | rowscale (16 KB)
    char* ws = (char*)d_ws;
    i8* Wqb = (i8*)ws;
    i8* Xq  = (i8*)(ws + (size_t)OUT_F * IN_F);
    float* rowsum   = (float*)(ws + (size_t)OUT_F * IN_F + (size_t)TOKENS * IN_F);
    float* rowscale = rowsum + TOKENS;

    prep_w_kernel<<<2048, 256, 0, stream>>>(wq, Wqb);
    prep_x_kernel<<<TOKENS, 256, 0, stream>>>(x, Xq, rowsum, rowscale);
    qgemm_kernel<<<MT * NT, 512, 0, stream>>>(Xq, Wqb, rowsum, rowscale,
                                              scale, zero, bias, out);
}